// Round 11
// baseline (111.810 us; speedup 1.0000x reference)
//
#include <hip/hip_runtime.h>
#include <hip/hip_fp16.h>

// Problem constants (from reference)
#define SPP   16
#define SH    256
#define SW    256
#define HI    1024
#define WI    1024
#define CH    3
#define BATCH 4

#define MAXR  10    // exact bound: ceil(step*maxdd*512)+4 = 5.25+4 -> 10 rows
#define RSTR  1028  // LDS row stride in half2 units (4112 B: 16B-aligned rows)
#define NTHR  256   // one sensor row per block, 1 px/thread

// tanh via v_exp_f32; |arg| <= ~1.2 here, abs error ~1e-6 (threshold 1.7e-2).
__device__ __forceinline__ float fast_tanh(float x) {
    const float e = __expf(2.0f * x);
    return (e - 1.0f) * __builtin_amdgcn_rcpf(e + 1.0f);
}

// R9 post-mortem: five structural levers (LDS size, caches, WG slots, async
// staging, occupancy) all left a ~35us floor. The numbers that DO move:
// achieved HBM rate is 1-1.9 TB/s in every variant (fills: 6.4 TB/s), and
// unique image traffic ~50-65 MB/iter (L3 flushed by the 268MB fill each
// iter) -> 60MB/1.8TB/s = 33us = the floor. Cause: all tilings fetch the
// image as ~200-B bbox row-fragments -> DRAM page locality destroyed.
// This version makes staging SEQUENTIAL: one block = one full sensor row;
// footprint = <=10 COMPLETE image rows -> 4-KB contiguous float4 runs.
// Vertical halo re-reads hit L2 (XCD swizzle keeps a contiguous row band
// per XCD). LDS fp16 planar 61.7 KB -> 2 blocks/CU.
__global__ __launch_bounds__(NTHR, 2) void foveated_row(
    const float* __restrict__ img,
    const float* __restrict__ t_ptr,
    const float* __restrict__ jitter,
    float* __restrict__ out)
{
    __shared__ __half2 RG[MAXR * RSTR];  // 41120 B  (R,G packed per px)
    __shared__ __half  Bp[MAXR * RSTR];  // 20560 B  (B plane)

    // 1024 blocks = 4 batches x 256 sensor rows. XCD swizzle: each XCD gets
    // 128 consecutive (batch,row) pairs -> concurrently-staged image rows
    // span ~3 MB, fits the XCD's 4 MB L2 -> halo re-reads are L2 hits.
    const int bid = blockIdx.x;
    const int L   = (bid & 7) * 128 + (bid >> 3);
    const int b   = L >> 8;
    const int sy  = L & 255;

    const int th = threadIdx.x;   // 0..255 = sensor column sx
    const int sx = th;

    const float step  = 2.0f / 256.0f;
    const float tt    = t_ptr[0];
    const float inv_s = __builtin_amdgcn_rcpf(fast_tanh(tt));

    auto gmap = [&](float p) {
        float g = (fast_tanh(tt * p) * inv_s + 1.0f) * 512.0f - 0.5f;
        return fminf(fmaxf(g, 0.0f), 1023.0f);
    };
    // Row band of this sensor row: posy in [pyrow, pyrow+step)  (jitter in [0,1))
    const float pyrow = -1.0f + sy * step;
    const int y_lo  = max((int)gmap(pyrow) - 1, 0);
    const int y_hi  = min((int)gmap(pyrow + step) + 2, HI - 1);
    const int nrows = y_hi - y_lo + 1;
    const bool fits = (nrows > 0) && (nrows <= MAXR);   // always true at t=1

    const size_t plane = (size_t)HI * WI;
    const float* __restrict__ p0 = img + (size_t)(b * CH) * plane;
    const float* __restrict__ p1 = p0 + plane;
    const float* __restrict__ p2 = p1 + plane;

    const float px = -1.0f + sx * step;
    const float py = pyrow;

    // ---- All 16 jitter loads first (coalesced; named regs, static use) ----
    const float2* __restrict__ jit2 = (const float2*)jitter;
    const int jbase = sy * SW + sx;
    const float2 jv0  = jit2[jbase +  0 * (SH * SW)];
    const float2 jv1  = jit2[jbase +  1 * (SH * SW)];
    const float2 jv2  = jit2[jbase +  2 * (SH * SW)];
    const float2 jv3  = jit2[jbase +  3 * (SH * SW)];
    const float2 jv4  = jit2[jbase +  4 * (SH * SW)];
    const float2 jv5  = jit2[jbase +  5 * (SH * SW)];
    const float2 jv6  = jit2[jbase +  6 * (SH * SW)];
    const float2 jv7  = jit2[jbase +  7 * (SH * SW)];
    const float2 jv8  = jit2[jbase +  8 * (SH * SW)];
    const float2 jv9  = jit2[jbase +  9 * (SH * SW)];
    const float2 jv10 = jit2[jbase + 10 * (SH * SW)];
    const float2 jv11 = jit2[jbase + 11 * (SH * SW)];
    const float2 jv12 = jit2[jbase + 12 * (SH * SW)];
    const float2 jv13 = jit2[jbase + 13 * (SH * SW)];
    const float2 jv14 = jit2[jbase + 14 * (SH * SW)];
    const float2 jv15 = jit2[jbase + 15 * (SH * SW)];

    float acc0 = 0.0f, acc1 = 0.0f, acc2 = 0.0f, dsum = 0.0f;

    auto sample_lds = [&](float jx, float jy) {
        const float posx = px + jx * step;
        const float posy = py + jy * step;

        const float thx = fast_tanh(tt * posx);
        const float thy = fast_tanh(tt * posy);
        const float ddx = tt * (1.0f - thx * thx) * inv_s;
        const float ddy = tt * (1.0f - thy * thy) * inv_s;
        const float det = ddx * ddy;

        float gx = (thx * inv_s + 1.0f) * 512.0f - 0.5f;
        float gy = (thy * inv_s + 1.0f) * 512.0f - 0.5f;
        gx = fminf(fmaxf(gx, 0.0f), (float)(WI - 1));
        gy = fminf(fmaxf(gy, 0.0f), (float)(HI - 1));

        const int xb = min((int)gx, WI - 2);
        const int yb = min((int)gy, HI - 2);
        const float fx = gx - (float)xb;
        const float fy = gy - (float)yb;

        const float w00 = (1.0f - fx) * (1.0f - fy) * det;
        const float w01 = fx * (1.0f - fy) * det;
        const float w10 = (1.0f - fx) * fy * det;
        const float w11 = fx * fy * det;
        dsum += det;

        const int o   = (yb - y_lo) * RSTR + xb;
        const int o1  = o + RSTR;
        const float2 f00 = __half22float2(RG[o]);
        const float2 f01 = __half22float2(RG[o + 1]);
        const float2 f10 = __half22float2(RG[o1]);
        const float2 f11 = __half22float2(RG[o1 + 1]);
        const float v00 = __half2float(Bp[o]);
        const float v01 = __half2float(Bp[o + 1]);
        const float v10 = __half2float(Bp[o1]);
        const float v11 = __half2float(Bp[o1 + 1]);

        acc0 += w00 * f00.x + w01 * f01.x + w10 * f10.x + w11 * f11.x;
        acc1 += w00 * f00.y + w01 * f01.y + w10 * f10.y + w11 * f11.y;
        acc2 += w00 * v00   + w01 * v01   + w10 * v10   + w11 * v11;
    };

    auto sample_glb = [&](float jx, float jy) {
        const float posx = px + jx * step;
        const float posy = py + jy * step;

        const float thx = fast_tanh(tt * posx);
        const float thy = fast_tanh(tt * posy);
        const float ddx = tt * (1.0f - thx * thx) * inv_s;
        const float ddy = tt * (1.0f - thy * thy) * inv_s;
        const float det = ddx * ddy;

        float gx = (thx * inv_s + 1.0f) * 512.0f - 0.5f;
        float gy = (thy * inv_s + 1.0f) * 512.0f - 0.5f;
        gx = fminf(fmaxf(gx, 0.0f), (float)(WI - 1));
        gy = fminf(fmaxf(gy, 0.0f), (float)(HI - 1));

        const int xb = min((int)gx, WI - 2);
        const int yb = min((int)gy, HI - 2);
        const float fx = gx - (float)xb;
        const float fy = gy - (float)yb;

        const float w00 = (1.0f - fx) * (1.0f - fy) * det;
        const float w01 = fx * (1.0f - fy) * det;
        const float w10 = (1.0f - fx) * fy * det;
        const float w11 = fx * fy * det;
        dsum += det;

        const int i0 = yb * WI + xb;
        const int i1 = i0 + WI;
        { const float a0 = p0[i0], a1 = p0[i0 + 1], c0 = p0[i1], c1 = p0[i1 + 1];
          acc0 += a0 * w00 + a1 * w01 + c0 * w10 + c1 * w11; }
        { const float a0 = p1[i0], a1 = p1[i0 + 1], c0 = p1[i1], c1 = p1[i1 + 1];
          acc1 += a0 * w00 + a1 * w01 + c0 * w10 + c1 * w11; }
        { const float a0 = p2[i0], a1 = p2[i0 + 1], c0 = p2[i1], c1 = p2[i1 + 1];
          acc2 += a0 * w00 + a1 * w01 + c0 * w10 + c1 * w11; }
    };

    if (fits) {
        // ---- Stage <=10 FULL image rows -> LDS fp16. Each thread: one
        // float4 (4 px) per row per channel -> 4-KB contiguous runs per row
        // per plane across the block (pure sequential DRAM bursts).
        // A/B 2-deep pipeline: row r+1's loads fly under row r's cvt+write. ----
        const int c0 = th * 4;
        float4 rA, gA, bA, rB, gB, bB;

        #define ISSUE(r, RR, GG, BB)                                         \
            if ((r) < nrows) {                                               \
                const float* rowp = p0 + (size_t)(y_lo + (r)) * WI + c0;     \
                RR = *(const float4*)(rowp);                                 \
                GG = *(const float4*)(rowp + plane);                         \
                BB = *(const float4*)(rowp + 2 * plane);                     \
            }
        #define COMMIT(r, RR, GG, BB)                                        \
            if ((r) < nrows) {                                               \
                const int o = (r) * RSTR + c0;                               \
                union { __half2 h[4]; uint4 u; } vv;                         \
                vv.h[0] = __floats2half2_rn(RR.x, GG.x);                     \
                vv.h[1] = __floats2half2_rn(RR.y, GG.y);                     \
                vv.h[2] = __floats2half2_rn(RR.z, GG.z);                     \
                vv.h[3] = __floats2half2_rn(RR.w, GG.w);                     \
                *(uint4*)&RG[o] = vv.u;                                      \
                union { __half2 h[2]; uint2 u; } bb;                         \
                bb.h[0] = __floats2half2_rn(BB.x, BB.y);                     \
                bb.h[1] = __floats2half2_rn(BB.z, BB.w);                     \
                *(uint2*)&Bp[o] = bb.u;                                      \
            }

        ISSUE (0, rA, gA, bA);
        ISSUE (1, rB, gB, bB);
        COMMIT(0, rA, gA, bA);
        ISSUE (2, rA, gA, bA);
        COMMIT(1, rB, gB, bB);
        ISSUE (3, rB, gB, bB);
        COMMIT(2, rA, gA, bA);
        ISSUE (4, rA, gA, bA);
        COMMIT(3, rB, gB, bB);
        ISSUE (5, rB, gB, bB);
        COMMIT(4, rA, gA, bA);
        ISSUE (6, rA, gA, bA);
        COMMIT(5, rB, gB, bB);
        ISSUE (7, rB, gB, bB);
        COMMIT(6, rA, gA, bA);
        ISSUE (8, rA, gA, bA);
        COMMIT(7, rB, gB, bB);
        ISSUE (9, rB, gB, bB);
        COMMIT(8, rA, gA, bA);
        COMMIT(9, rB, gB, bB);

        #undef ISSUE
        #undef COMMIT

        __syncthreads();

        // ---- This lane's 16 spp from LDS (fully unrolled) ----
        sample_lds(jv0.x,  jv0.y);   sample_lds(jv1.x,  jv1.y);
        sample_lds(jv2.x,  jv2.y);   sample_lds(jv3.x,  jv3.y);
        sample_lds(jv4.x,  jv4.y);   sample_lds(jv5.x,  jv5.y);
        sample_lds(jv6.x,  jv6.y);   sample_lds(jv7.x,  jv7.y);
        sample_lds(jv8.x,  jv8.y);   sample_lds(jv9.x,  jv9.y);
        sample_lds(jv10.x, jv10.y);  sample_lds(jv11.x, jv11.y);
        sample_lds(jv12.x, jv12.y);  sample_lds(jv13.x, jv13.y);
        sample_lds(jv14.x, jv14.y);  sample_lds(jv15.x, jv15.y);
    } else {
        // ---- Fallback: direct global gathers (never taken at t=1) ----
        sample_glb(jv0.x,  jv0.y);   sample_glb(jv1.x,  jv1.y);
        sample_glb(jv2.x,  jv2.y);   sample_glb(jv3.x,  jv3.y);
        sample_glb(jv4.x,  jv4.y);   sample_glb(jv5.x,  jv5.y);
        sample_glb(jv6.x,  jv6.y);   sample_glb(jv7.x,  jv7.y);
        sample_glb(jv8.x,  jv8.y);   sample_glb(jv9.x,  jv9.y);
        sample_glb(jv10.x, jv10.y);  sample_glb(jv11.x, jv11.y);
        sample_glb(jv12.x, jv12.y);  sample_glb(jv13.x, jv13.y);
        sample_glb(jv14.x, jv14.y);  sample_glb(jv15.x, jv15.y);
    }

    // ---- 1 px per thread: contiguous stores ----
    const float inv_d = 1.0f / dsum;
    const int pix = sy * SW + sx;
    const size_t ob = (size_t)b * CH * (SH * SW) + pix;
    out[ob]                 = acc0 * inv_d;
    out[ob + (SH * SW)]     = acc1 * inv_d;
    out[ob + 2 * (SH * SW)] = acc2 * inv_d;
}

extern "C" void kernel_launch(void* const* d_in, const int* in_sizes, int n_in,
                              void* d_out, int out_size, void* d_ws, size_t ws_size,
                              hipStream_t stream) {
    const float* img    = (const float*)d_in[0];
    const float* t      = (const float*)d_in[1];
    const float* jitter = (const float*)d_in[2];
    float* out          = (float*)d_out;

    // 4 batches x 256 sensor rows = 1024 blocks, 256 threads (1 px each)
    hipLaunchKernelGGL(foveated_row, dim3(1024), dim3(NTHR), 0, stream,
                       img, t, jitter, out);
}